// Round 6
// baseline (216.896 us; speedup 1.0000x reference)
//
#include <hip/hip_runtime.h>
#include <hip/hip_bf16.h>
#include <math.h>

#define H_ 1024
#define NH_ 16
#define HD_ 64
#define B_ 2
#define SQ_ 2048
#define SK_ 2048

using bf16x8 = __attribute__((ext_vector_type(8))) short;
using f32x4  = __attribute__((ext_vector_type(4))) float;

static __device__ __forceinline__ unsigned short f2bf(float f) {
  union { float f; unsigned u; } v; v.f = f;
  unsigned r = v.u + 0x7fffu + ((v.u >> 16) & 1u);
  return (unsigned short)(r >> 16);
}
static __device__ __forceinline__ float bf2f(unsigned short u) {
  union { unsigned u; float f; } c; c.u = (unsigned)u << 16;
  return c.f;
}

// pack two f32 -> two bf16 (round-half-up) in one dword: [a(lo), b(hi)]
static __device__ __forceinline__ unsigned pack_bf(float a, float b) {
  union { float f; unsigned u; } ua, ub;
  ua.f = a; ub.f = b;
  return __builtin_amdgcn_perm(ub.u + 0x8000u, ua.u + 0x8000u, 0x07060302u);
}

static __device__ __forceinline__ void gl2lds16(const void* g, void* l) {
  __builtin_amdgcn_global_load_lds(
      (const __attribute__((address_space(1))) unsigned int*)g,
      (__attribute__((address_space(3))) unsigned int*)l, 16, 0, 0);
}

// swizzled index (shorts) within a [rows][64-short] tile, 128B rows
static __device__ __forceinline__ int sidx(int row, int cbyte) {
  return row * 64 + (((cbyte) ^ ((row & 7) << 4)) >> 1);
}

// ---------------- f32 -> bf16 convert (8 elems/thread) ----------------
__global__ __launch_bounds__(256) void conv_bf16(
    const float* __restrict__ src, unsigned short* __restrict__ dst,
    int rows, int cols, int ld_src, int ld_dst) {
  long total = (long)rows * cols / 8;
  for (long i = blockIdx.x * (long)blockDim.x + threadIdx.x; i < total;
       i += (long)gridDim.x * blockDim.x) {
    long e = i * 8;
    int r = (int)(e / cols);
    int c = (int)(e % cols);
    const float* s = src + (long)r * ld_src + c;
    unsigned short tmp[8];
#pragma unroll
    for (int j = 0; j < 8; ++j) tmp[j] = f2bf(s[j]);
    *(uint4*)(dst + (long)r * ld_dst + c) = *(uint4*)tmp;
  }
}

// ---------------- f32 (R,C) -> bf16 transposed (C,R) ----------------
__global__ __launch_bounds__(256) void convT(
    const float* __restrict__ in, unsigned short* __restrict__ out, int R, int C) {
  __shared__ __align__(16) unsigned short Ls[64][68];
  int nct = C >> 6;
  int tr = blockIdx.x / nct, tc = blockIdx.x % nct;
  int r0 = tr * 64, c0 = tc * 64;
  int rr = threadIdx.x >> 4;
  int cc = (threadIdx.x & 15) * 4;
#pragma unroll
  for (int i = 0; i < 4; ++i) {
    int r = rr + 16 * i;
    float4 v = *(const float4*)&in[(long)(r0 + r) * C + c0 + cc];
    unsigned short t[4] = {f2bf(v.x), f2bf(v.y), f2bf(v.z), f2bf(v.w)};
    *(unsigned long long*)&Ls[r][cc] = *(unsigned long long*)t;
  }
  __syncthreads();
  int oc = threadIdx.x >> 2;
  int orr = (threadIdx.x & 3) * 16;
  unsigned short t[16];
#pragma unroll
  for (int j = 0; j < 16; ++j) t[j] = Ls[orr + j][oc];
  *(uint4*)&out[(long)(c0 + oc) * R + r0 + orr] = *(uint4*)&t[0];
  *(uint4*)&out[(long)(c0 + oc) * R + r0 + orr + 8] = *(uint4*)&t[8];
}

// ---------------- b_eff = mlp_b + c_proj_b @ W2  (one wave per output) -----
__global__ __launch_bounds__(256) void bias_fold(
    const float* __restrict__ mlp_b, const float* __restrict__ cpb,
    const unsigned short* __restrict__ w_mlT,  // (1024, 2048), cols 1024.. = W2^T
    float* __restrict__ beff) {
  int wv = threadIdx.x >> 6, l = threadIdx.x & 63;
  int j = blockIdx.x * 4 + wv;
  float s = 0.f;
#pragma unroll
  for (int i0 = 0; i0 < 1024; i0 += 64)
    s += cpb[i0 + l] * bf2f(w_mlT[(long)j * 2048 + 1024 + i0 + l]);
  for (int d = 1; d < 64; d <<= 1) s += __shfl_xor(s, d);
  if (l == 0) beff[j] = mlp_b[j] + s;
}

// ---------------- bf16 GEMM, B^T input, BK=64, double-buffered, swizzled ----
// Out = A(MxK) @ W(KxN) + bias, Bw = W^T (N rows, K cols). BN = 128 (NF=4).
// MODE 0: bf16 out0. MODE 1: f32 out0 + GELU. DUALB: k>=1024 reads Bw2 (ld 1024).
template <int MODE, bool DUALB>
__global__ __launch_bounds__(256) void gemm_bt(
    const unsigned short* __restrict__ A, int lda,
    const unsigned short* __restrict__ Bw, int ldb,
    const unsigned short* __restrict__ Bw2,
    const float* __restrict__ bias,
    void* __restrict__ out0, int ldo, int K) {
  __shared__ __align__(16) unsigned short Al[2][128 * 64];
  __shared__ __align__(16) unsigned short Bl[2][128 * 64];
  const int tid = threadIdx.x;
  const int l = tid & 63, w = tid >> 6;
  const int wr = w >> 1, wc = w & 1;
  const int lq = l & 15, lh = l >> 4;
  const int m0 = blockIdx.y * 128, n0 = blockIdx.x * 128;

  const int swcol = (((tid & 7) ^ ((tid >> 3) & 7)) << 3);  // shorts
  const int rbase = w * 8 + (l >> 3);
  const unsigned short* gA = A + (long)(m0 + rbase) * lda + swcol;
  const unsigned short* gB = Bw + (long)(n0 + rbase) * ldb + swcol;
  const unsigned short* gB2 =
      DUALB ? Bw2 + (long)(n0 + rbase) * 1024 + swcol : nullptr;

  f32x4 acc[4][4];
#pragma unroll
  for (int a = 0; a < 4; ++a)
#pragma unroll
    for (int b = 0; b < 4; ++b) acc[a][b] = (f32x4){0.f, 0.f, 0.f, 0.f};

  auto stage = [&](int k0, int buf) {
#pragma unroll
    for (int i = 0; i < 4; ++i)
      gl2lds16(gA + (long)(i * 32) * lda + k0, &Al[buf][i * 2048 + w * 512]);
    if (DUALB && k0 >= 1024) {
#pragma unroll
      for (int i = 0; i < 4; ++i)
        gl2lds16(gB2 + (long)(i * 32) * 1024 + (k0 - 1024),
                 &Bl[buf][i * 2048 + w * 512]);
    } else {
#pragma unroll
      for (int i = 0; i < 4; ++i)
        gl2lds16(gB + (long)(i * 32) * ldb + k0, &Bl[buf][i * 2048 + w * 512]);
    }
  };

  const int NT = K >> 6;
  stage(0, 0);
  __syncthreads();
  int cur = 0;
  for (int t = 0; t < NT; ++t) {
    if (t + 1 < NT) stage((t + 1) << 6, cur ^ 1);
    bf16x8 af[4][2], bfr[4][2];
#pragma unroll
    for (int a = 0; a < 4; ++a) {
      int row = wr * 64 + a * 16 + lq;
#pragma unroll
      for (int kk = 0; kk < 2; ++kk)
        af[a][kk] = *(const bf16x8*)&Al[cur][sidx(row, kk * 64 + lh * 16)];
    }
#pragma unroll
    for (int b = 0; b < 4; ++b) {
      int row = wc * 64 + b * 16 + lq;
#pragma unroll
      for (int kk = 0; kk < 2; ++kk)
        bfr[b][kk] = *(const bf16x8*)&Bl[cur][sidx(row, kk * 64 + lh * 16)];
    }
#pragma unroll
    for (int kk = 0; kk < 2; ++kk)
#pragma unroll
      for (int a = 0; a < 4; ++a)
#pragma unroll
        for (int b = 0; b < 4; ++b)
          acc[a][b] = __builtin_amdgcn_mfma_f32_16x16x32_bf16(
              af[a][kk], bfr[b][kk], acc[a][b], 0, 0, 0);
    __syncthreads();
    cur ^= 1;
  }

#pragma unroll
  for (int a = 0; a < 4; ++a) {
#pragma unroll
    for (int bb = 0; bb < 4; ++bb) {
      int col = n0 + wc * 64 + bb * 16 + lq;
      float bv = bias[col];
      int row0 = m0 + wr * 64 + a * 16 + lh * 4;
      if (MODE == 0) {
        unsigned short* O = (unsigned short*)out0;
#pragma unroll
        for (int r = 0; r < 4; ++r)
          O[(long)(row0 + r) * ldo + col] = f2bf(acc[a][bb][r] + bv);
      } else {
        float* O = (float*)out0;
#pragma unroll
        for (int r = 0; r < 4; ++r) {
          float v = acc[a][bb][r] + bv;
          float y = 0.7978845608028654f * (v + 0.044715f * v * v * v);
          O[(long)(row0 + r) * ldo + col] =
              v * __builtin_amdgcn_rcpf(1.f + __expf(-2.f * y));
        }
      }
    }
  }
}

// ---------------- merged QKV GEMM -------------------------------------------
// grid (24, 32). x<8: Q = cat[:, :1024] @ W[:, :1024]; x>=8: KV from aet.
// Epilogue by global col: [0,1024) Q; [1024,2048) K*mask; [2048,3072) V^T.
__global__ __launch_bounds__(256) void gemm_qkv(
    const unsigned short* __restrict__ Acat,  // 4096 x 2048 (cols 0..1024 used)
    const unsigned short* __restrict__ Aet,   // 4096 x 1024
    const unsigned short* __restrict__ Bw,    // w_atT 3072 x 1024
    const float* __restrict__ bias,           // c_attn_b (3072)
    const int* __restrict__ msk,              // (B*SK)
    unsigned short* __restrict__ Qb,          // 4096 x 1024
    unsigned short* __restrict__ Kb,          // 4096 x 1024
    unsigned short* __restrict__ Vtg) {       // (B, NH, HD, SK)
  __shared__ __align__(16) unsigned short Al[2][128 * 64];
  __shared__ __align__(16) unsigned short Bl[2][128 * 64];
  const int tid = threadIdx.x;
  const int l = tid & 63, w = tid >> 6;
  const int wr = w >> 1, wc = w & 1;
  const int lq = l & 15, lh = l >> 4;
  const int bx = blockIdx.x;
  const int m0 = blockIdx.y * 128, n0 = bx * 128;
  const unsigned short* A;
  int lda;
  if (bx < 8) { A = Acat; lda = 2048; } else { A = Aet; lda = 1024; }

  const int swcol = (((tid & 7) ^ ((tid >> 3) & 7)) << 3);
  const int rbase = w * 8 + (l >> 3);
  const unsigned short* gA = A + (long)(m0 + rbase) * lda + swcol;
  const unsigned short* gB = Bw + (long)(n0 + rbase) * 1024 + swcol;

  f32x4 acc[4][4];
#pragma unroll
  for (int a = 0; a < 4; ++a)
#pragma unroll
    for (int b = 0; b < 4; ++b) acc[a][b] = (f32x4){0.f, 0.f, 0.f, 0.f};

  auto stage = [&](int k0, int buf) {
#pragma unroll
    for (int i = 0; i < 4; ++i)
      gl2lds16(gA + (long)(i * 32) * lda + k0, &Al[buf][i * 2048 + w * 512]);
#pragma unroll
    for (int i = 0; i < 4; ++i)
      gl2lds16(gB + (long)(i * 32) * 1024 + k0, &Bl[buf][i * 2048 + w * 512]);
  };

  stage(0, 0);
  __syncthreads();
  int cur = 0;
  for (int t = 0; t < 16; ++t) {
    if (t + 1 < 16) stage((t + 1) << 6, cur ^ 1);
    bf16x8 af[4][2], bfr[4][2];
#pragma unroll
    for (int a = 0; a < 4; ++a) {
      int row = wr * 64 + a * 16 + lq;
#pragma unroll
      for (int kk = 0; kk < 2; ++kk)
        af[a][kk] = *(const bf16x8*)&Al[cur][sidx(row, kk * 64 + lh * 16)];
    }
#pragma unroll
    for (int b = 0; b < 4; ++b) {
      int row = wc * 64 + b * 16 + lq;
#pragma unroll
      for (int kk = 0; kk < 2; ++kk)
        bfr[b][kk] = *(const bf16x8*)&Bl[cur][sidx(row, kk * 64 + lh * 16)];
    }
#pragma unroll
    for (int kk = 0; kk < 2; ++kk)
#pragma unroll
      for (int a = 0; a < 4; ++a)
#pragma unroll
        for (int b = 0; b < 4; ++b)
          acc[a][b] = __builtin_amdgcn_mfma_f32_16x16x32_bf16(
              af[a][kk], bfr[b][kk], acc[a][b], 0, 0, 0);
    __syncthreads();
    cur ^= 1;
  }

#pragma unroll
  for (int a = 0; a < 4; ++a) {
#pragma unroll
    for (int bb = 0; bb < 4; ++bb) {
      int col = n0 + wc * 64 + bb * 16 + lq;
      float bv = bias[col];
      int row0 = m0 + wr * 64 + a * 16 + lh * 4;
      if (col < 1024) {
#pragma unroll
        for (int r = 0; r < 4; ++r)
          Qb[(long)(row0 + r) * 1024 + col] = f2bf(acc[a][bb][r] + bv);
      } else if (col < 2048) {
        int kcol = col - 1024;
#pragma unroll
        for (int r = 0; r < 4; ++r) {
          float mk = (float)msk[row0 + r];
          Kb[(long)(row0 + r) * 1024 + kcol] = f2bf((acc[a][bb][r] + bv) * mk);
        }
      } else {
        int vcol = col - 2048, hh = vcol >> 6, dd = vcol & 63;
        int bi = row0 >> 11, k = row0 & 2047;
        unsigned short t[4];
#pragma unroll
        for (int r = 0; r < 4; ++r) t[r] = f2bf(acc[a][bb][r] + bv);
        *(unsigned long long*)(Vtg + (((long)(bi * NH_ + hh) * HD_ + dd) << 11) + k) =
            *(unsigned long long*)t;
      }
    }
  }
}

// ---------------- flash attention: LDS+swizzle staging, no-max softmax ------
// grid (SQ/64, NH, B), block 256 = 4 waves x 16 q-rows. KV tiles of 64.
// K pre-masked (B*SK, H); V pre-transposed (B, NH, HD, SK).
__global__ __launch_bounds__(256) void flash_attn(
    const unsigned short* __restrict__ Qb,
    const unsigned short* __restrict__ Kb,
    const unsigned short* __restrict__ Vtg,
    unsigned short* __restrict__ Ob, int ldo) {
  __shared__ __align__(16) unsigned short Kl[64 * 64];
  __shared__ __align__(16) unsigned short Vt[64 * 64];  // Vt[d][k]
  __shared__ __align__(16) unsigned short Pl[4][1024];
  const int tid = threadIdx.x;
  const int l = tid & 63, w = tid >> 6;
  const int qb = blockIdx.x, h = blockIdx.y, b = blockIdx.z;
  const int lq = l & 15, lh = l >> 4;

  const long qrow = (long)b * SQ_ + qb * 64 + w * 16 + lq;
  const unsigned short* qp = Qb + qrow * H_ + h * HD_;
  const bf16x8 qf0 = *(const bf16x8*)(qp + lh * 8);
  const bf16x8 qf1 = *(const bf16x8*)(qp + 32 + lh * 8);

  const int sr = tid >> 2, scs = (tid & 3) * 16;
  const unsigned short* Kg = Kb + ((long)b * SK_ + sr) * H_ + h * HD_ + scs;
  const unsigned short* Vg = Vtg + ((long)(b * NH_ + h) * HD_ + sr) * SK_ + scs;
  const int wi0 = sidx(sr, (tid & 3) * 32);
  const int wi1 = sidx(sr, (tid & 3) * 32 + 16);

  uint4 kr0 = *(const uint4*)Kg, kr1 = *(const uint4*)(Kg + 8);
  uint4 vr0 = *(const uint4*)Vg, vr1 = *(const uint4*)(Vg + 8);
  *(uint4*)&Kl[wi0] = kr0;
  *(uint4*)&Kl[wi1] = kr1;
  *(uint4*)&Vt[wi0] = vr0;
  *(uint4*)&Vt[wi1] = vr1;

  unsigned short* Pw = Pl[w];
  const float C1 = 1.4426950408889634f;   // 1/ln2
  const float C2 = 23.083120654223414f;   // 16/ln2  (P = exp(s-16))

  float l_run = 0.f;
  f32x4 accO[4];
#pragma unroll
  for (int ms = 0; ms < 4; ++ms) accO[ms] = (f32x4){0.f, 0.f, 0.f, 0.f};

  const int NT = SK_ / 64;
  for (int kt = 0; kt < NT; ++kt) {
    __syncthreads();
    if (kt + 1 < NT) {
      const unsigned short* kp = Kg + (long)(kt + 1) * 64 * H_;
      kr0 = *(const uint4*)kp;
      kr1 = *(const uint4*)(kp + 8);
      vr0 = *(const uint4*)(Vg + (kt + 1) * 64);
      vr1 = *(const uint4*)(Vg + (kt + 1) * 64 + 8);
    }

    f32x4 s[4];
    __builtin_amdgcn_s_setprio(1);
#pragma unroll
    for (int ms = 0; ms < 4; ++ms) {
      int row = ms * 16 + lq;
      bf16x8 a0 = *(const bf16x8*)&Kl[sidx(row, lh * 16)];
      bf16x8 a1 = *(const bf16x8*)&Kl[sidx(row, 64 + lh * 16)];
      f32x4 z = (f32x4){0.f, 0.f, 0.f, 0.f};
      z = __builtin_amdgcn_mfma_f32_16x16x32_bf16(a0, qf0, z, 0, 0, 0);
      z = __builtin_amdgcn_mfma_f32_16x16x32_bf16(a1, qf1, z, 0, 0, 0);
      s[ms] = z;
    }
    __builtin_amdgcn_s_setprio(0);
#pragma unroll
    for (int ms = 0; ms < 4; ++ms) {
      float p0 = exp2f(fmaf(s[ms][0], C1, -C2));
      float p1 = exp2f(fmaf(s[ms][1], C1, -C2));
      float p2 = exp2f(fmaf(s[ms][2], C1, -C2));
      float p3 = exp2f(fmaf(s[ms][3], C1, -C2));
      l_run += (p0 + p1) + (p2 + p3);
      unsigned pk[2] = {pack_bf(p0, p1), pack_bf(p2, p3)};
      *(unsigned long long*)&Pw[sidx(lq, ms * 32 + lh * 8)] =
          *(unsigned long long*)pk;
    }
    bf16x8 pb0 = *(const bf16x8*)&Pw[sidx(lq, lh * 16)];
    bf16x8 pb1 = *(const bf16x8*)&Pw[sidx(lq, 64 + lh * 16)];
    __builtin_amdgcn_s_setprio(1);
#pragma unroll
    for (int ms = 0; ms < 4; ++ms) {
      int row = ms * 16 + lq;
      bf16x8 v0 = *(const bf16x8*)&Vt[sidx(row, lh * 16)];
      bf16x8 v1 = *(const bf16x8*)&Vt[sidx(row, 64 + lh * 16)];
      accO[ms] = __builtin_amdgcn_mfma_f32_16x16x32_bf16(v0, pb0, accO[ms], 0, 0, 0);
      accO[ms] = __builtin_amdgcn_mfma_f32_16x16x32_bf16(v1, pb1, accO[ms], 0, 0, 0);
    }
    __builtin_amdgcn_s_setprio(0);
    __syncthreads();
    if (kt + 1 < NT) {
      *(uint4*)&Kl[wi0] = kr0;
      *(uint4*)&Kl[wi1] = kr1;
      *(uint4*)&Vt[wi0] = vr0;
      *(uint4*)&Vt[wi1] = vr1;
    }
  }

  l_run += __shfl_xor(l_run, 16);
  l_run += __shfl_xor(l_run, 32);
  float rs = 1.f / l_run;
  long orow = (long)b * SQ_ + qb * 64 + w * 16 + lq;
#pragma unroll
  for (int ms = 0; ms < 4; ++ms) {
    unsigned short ou[4];
#pragma unroll
    for (int r = 0; r < 4; ++r) ou[r] = f2bf(accO[ms][r] * rs);
    *(unsigned long long*)(Ob + orow * ldo + h * HD_ + ms * 16 + lh * 4) =
        *(unsigned long long*)ou;
  }
}

extern "C" void kernel_launch(void* const* d_in, const int* in_sizes, int n_in,
                              void* d_out, int out_size, void* d_ws, size_t ws_size,
                              hipStream_t stream) {
  (void)in_sizes; (void)n_in; (void)out_size; (void)ws_size;
  const float* attender = (const float*)d_in[0];
  const float* attendee = (const float*)d_in[1];
  const int*   mask     = (const int*)d_in[2];
  const float* c_attn_w = (const float*)d_in[3];
  const float* c_attn_b = (const float*)d_in[4];
  const float* c_proj_w = (const float*)d_in[5];
  const float* c_proj_b = (const float*)d_in[6];
  const float* mlp_w    = (const float*)d_in[7];
  const float* mlp_b    = (const float*)d_in[8];
  float* out = (float*)d_out;

  char* ws = (char*)d_ws;
  size_t off = 0;
  auto alloc = [&](size_t bytes) {
    void* p = ws + off;
    off += (bytes + 255) & ~(size_t)255;
    return p;
  };
  unsigned short* cat   = (unsigned short*)alloc((size_t)4096 * 2048 * 2); // [attender_bf | attn]
  unsigned short* aet   = (unsigned short*)alloc((size_t)4096 * 1024 * 2);
  unsigned short* w_atT = (unsigned short*)alloc((size_t)3072 * 1024 * 2); // (3H, H)
  unsigned short* w_pr  = (unsigned short*)alloc((size_t)1024 * 1024 * 2); // bf16(c_proj_w)
  unsigned short* w_mlT = (unsigned short*)alloc((size_t)1024 * 2048 * 2); // (H, 2H)
  unsigned short* weffT = (unsigned short*)alloc((size_t)1024 * 1024 * 2); // (W_pr@W2)^T
  unsigned short* Qb    = (unsigned short*)alloc((size_t)4096 * 1024 * 2);
  unsigned short* Kbuf  = (unsigned short*)alloc((size_t)4096 * 1024 * 2);
  unsigned short* Vtg   = (unsigned short*)alloc((size_t)B_ * NH_ * HD_ * SK_ * 2);
  float* beff = (float*)alloc(1024 * 4);
  float* zbuf = (float*)alloc(1024 * 4);

  hipMemsetAsync(zbuf, 0, 1024 * 4, stream);
  conv_bf16<<<2048, 256, 0, stream>>>(attender, cat, 4096, 1024, 1024, 2048);
  conv_bf16<<<2048, 256, 0, stream>>>(attendee, aet, 4096, 1024, 1024, 1024);
  convT<<<768, 256, 0, stream>>>(c_attn_w, w_atT, 1024, 3072);
  conv_bf16<<<512, 256, 0, stream>>>(c_proj_w, w_pr, 1024, 1024, 1024, 1024);
  convT<<<512, 256, 0, stream>>>(mlp_w, w_mlT, 2048, 1024);

  // b_eff = mlp_b + c_proj_b @ W2
  bias_fold<<<256, 256, 0, stream>>>(mlp_b, c_proj_b, w_mlT, beff);
  // W_eff^T = W2^T @ Wpr^T  (A = w_mlT[:,1024:], Bw = bf16(c_proj_w))
  gemm_bt<0, false><<<dim3(8, 8), 256, 0, stream>>>(
      w_mlT + 1024, 2048, w_pr, 1024, nullptr, zbuf, weffT, 1024, 1024);
  // Q | K*mask | V^T in one launch
  gemm_qkv<<<dim3(24, 32), 256, 0, stream>>>(
      cat, aet, w_atT, c_attn_b, mask, Qb, Kbuf, Vtg);
  // attention -> cat[:, 1024:2048]
  flash_attn<<<dim3(32, 16, 2), 256, 0, stream>>>(Qb, Kbuf, Vtg, cat + 1024, 2048);
  // out = gelu(cat @ [W1; W_eff] + b_eff), f32
  gemm_bt<1, true><<<dim3(8, 32), 256, 0, stream>>>(
      cat, 2048, w_mlT, 2048, weffT, beff, out, 1024, 2048);
}

// Round 7
// 195.418 us; speedup vs baseline: 1.1099x; 1.1099x over previous
//
#include <hip/hip_runtime.h>
#include <hip/hip_bf16.h>
#include <math.h>

#define H_ 1024
#define NH_ 16
#define HD_ 64
#define B_ 2
#define SQ_ 2048
#define SK_ 2048

using bf16x8 = __attribute__((ext_vector_type(8))) short;
using f32x4  = __attribute__((ext_vector_type(4))) float;

static __device__ __forceinline__ unsigned short f2bf(float f) {
  union { float f; unsigned u; } v; v.f = f;
  unsigned r = v.u + 0x7fffu + ((v.u >> 16) & 1u);
  return (unsigned short)(r >> 16);
}

// two f32 -> packed bf16x2 dword via HW cvt (lo = a, hi = b)
static __device__ __forceinline__ unsigned cvtpk(float a, float b) {
  unsigned r;
  asm("v_cvt_pk_bf16_f32 %0, %1, %2" : "=v"(r) : "v"(a), "v"(b));
  return r;
}

static __device__ __forceinline__ void gl2lds16(const void* g, void* l) {
  __builtin_amdgcn_global_load_lds(
      (const __attribute__((address_space(1))) unsigned int*)g,
      (__attribute__((address_space(3))) unsigned int*)l, 16, 0, 0);
}

// swizzled index (shorts) within a [rows][64-short] tile, 128B rows
static __device__ __forceinline__ int sidx(int row, int cbyte) {
  return row * 64 + (((cbyte) ^ ((row & 7) << 4)) >> 1);
}

// ---------------- f32 -> bf16 convert (8 elems/thread) ----------------
__global__ __launch_bounds__(256) void conv_bf16(
    const float* __restrict__ src, unsigned short* __restrict__ dst,
    int rows, int cols, int ld_src, int ld_dst) {
  long total = (long)rows * cols / 8;
  for (long i = blockIdx.x * (long)blockDim.x + threadIdx.x; i < total;
       i += (long)gridDim.x * blockDim.x) {
    long e = i * 8;
    int r = (int)(e / cols);
    int c = (int)(e % cols);
    const float* s = src + (long)r * ld_src + c;
    unsigned short tmp[8];
#pragma unroll
    for (int j = 0; j < 8; ++j) tmp[j] = f2bf(s[j]);
    *(uint4*)(dst + (long)r * ld_dst + c) = *(uint4*)tmp;
  }
}

// ---------------- f32 (R,C) -> bf16 transposed (C,R) ----------------
__global__ __launch_bounds__(256) void convT(
    const float* __restrict__ in, unsigned short* __restrict__ out, int R, int C) {
  __shared__ __align__(16) unsigned short Ls[64][68];
  int nct = C >> 6;
  int tr = blockIdx.x / nct, tc = blockIdx.x % nct;
  int r0 = tr * 64, c0 = tc * 64;
  int rr = threadIdx.x >> 4;
  int cc = (threadIdx.x & 15) * 4;
#pragma unroll
  for (int i = 0; i < 4; ++i) {
    int r = rr + 16 * i;
    float4 v = *(const float4*)&in[(long)(r0 + r) * C + c0 + cc];
    unsigned short t[4] = {f2bf(v.x), f2bf(v.y), f2bf(v.z), f2bf(v.w)};
    *(unsigned long long*)&Ls[r][cc] = *(unsigned long long*)t;
  }
  __syncthreads();
  int oc = threadIdx.x >> 2;
  int orr = (threadIdx.x & 3) * 16;
  unsigned short t[16];
#pragma unroll
  for (int j = 0; j < 16; ++j) t[j] = Ls[orr + j][oc];
  *(uint4*)&out[(long)(c0 + oc) * R + r0 + orr] = *(uint4*)&t[0];
  *(uint4*)&out[(long)(c0 + oc) * R + r0 + orr + 8] = *(uint4*)&t[8];
}

// ---------------- bf16 GEMM, B^T input, BK=64, double-buffered, swizzled ----
// Out = A(Mx K) @ W(KxN) + bias, Bw = W^T (N rows, K cols). BN = NF*32.
// MODE 0: bf16 out0. MODE 1: f32 out0 + GELU.
template <int NF, int MODE>
__global__ __launch_bounds__(256) void gemm_bt(
    const unsigned short* __restrict__ A, int lda,
    const unsigned short* __restrict__ Bw, int ldb,
    const float* __restrict__ bias,
    void* __restrict__ out0, int ldo, int K) {
  __shared__ __align__(16) unsigned short Al[2][128 * 64];
  __shared__ __align__(16) unsigned short Bl[2][NF * 32 * 64];
  const int tid = threadIdx.x;
  const int l = tid & 63, w = tid >> 6;
  const int wr = w >> 1, wc = w & 1;
  const int lq = l & 15, lh = l >> 4;
  const int m0 = blockIdx.y * 128, n0 = blockIdx.x * (NF * 32);

  const int swcol = (((tid & 7) ^ ((tid >> 3) & 7)) << 3);  // shorts
  const int rbase = w * 8 + (l >> 3);
  const unsigned short* gA = A + (long)(m0 + rbase) * lda + swcol;
  const unsigned short* gB = Bw + (long)(n0 + rbase) * ldb + swcol;

  f32x4 acc[4][NF];
#pragma unroll
  for (int a = 0; a < 4; ++a)
#pragma unroll
    for (int b = 0; b < NF; ++b) acc[a][b] = (f32x4){0.f, 0.f, 0.f, 0.f};

  auto stage = [&](int k0, int buf) {
#pragma unroll
    for (int i = 0; i < 4; ++i)
      gl2lds16(gA + (long)(i * 32) * lda + k0, &Al[buf][i * 2048 + w * 512]);
#pragma unroll
    for (int i = 0; i < NF; ++i)
      gl2lds16(gB + (long)(i * 32) * ldb + k0, &Bl[buf][i * 2048 + w * 512]);
  };

  const int NT = K >> 6;
  stage(0, 0);
  __syncthreads();
  int cur = 0;
  for (int t = 0; t < NT; ++t) {
    if (t + 1 < NT) stage((t + 1) << 6, cur ^ 1);
    bf16x8 af[4][2], bfr[NF][2];
#pragma unroll
    for (int a = 0; a < 4; ++a) {
      int row = wr * 64 + a * 16 + lq;
#pragma unroll
      for (int kk = 0; kk < 2; ++kk)
        af[a][kk] = *(const bf16x8*)&Al[cur][sidx(row, kk * 64 + lh * 16)];
    }
#pragma unroll
    for (int b = 0; b < NF; ++b) {
      int row = wc * (NF * 16) + b * 16 + lq;
#pragma unroll
      for (int kk = 0; kk < 2; ++kk)
        bfr[b][kk] = *(const bf16x8*)&Bl[cur][sidx(row, kk * 64 + lh * 16)];
    }
#pragma unroll
    for (int kk = 0; kk < 2; ++kk)
#pragma unroll
      for (int a = 0; a < 4; ++a)
#pragma unroll
        for (int b = 0; b < NF; ++b)
          acc[a][b] = __builtin_amdgcn_mfma_f32_16x16x32_bf16(
              af[a][kk], bfr[b][kk], acc[a][b], 0, 0, 0);
    __syncthreads();
    cur ^= 1;
  }

#pragma unroll
  for (int a = 0; a < 4; ++a) {
#pragma unroll
    for (int bb = 0; bb < NF; ++bb) {
      int col = n0 + wc * (NF * 16) + bb * 16 + lq;
      float bv = bias[col];
      int row0 = m0 + wr * 64 + a * 16 + lh * 4;
      if (MODE == 0) {
        unsigned short* O = (unsigned short*)out0;
#pragma unroll
        for (int r = 0; r < 4; ++r)
          O[(long)(row0 + r) * ldo + col] = f2bf(acc[a][bb][r] + bv);
      } else {
        float* O = (float*)out0;
#pragma unroll
        for (int r = 0; r < 4; ++r) {
          float v = acc[a][bb][r] + bv;
          float y = 0.7978845608028654f * (v + 0.044715f * v * v * v);
          O[(long)(row0 + r) * ldo + col] =
              v * __builtin_amdgcn_rcpf(1.f + __expf(-2.f * y));
        }
      }
    }
  }
}

// ---------------- merged QKV GEMM -------------------------------------------
// grid (24, 32). x<8: Q = cat[:, :1024] @ W[:, :1024]; x>=8: KV from aet.
// Epilogue by global col: [0,1024) Q; [1024,2048) K*mask; [2048,3072) V^T.
__global__ __launch_bounds__(256) void gemm_qkv(
    const unsigned short* __restrict__ Acat,  // 4096 x 2048 (cols 0..1024 used)
    const unsigned short* __restrict__ Aet,   // 4096 x 1024
    const unsigned short* __restrict__ Bw,    // w_atT 3072 x 1024
    const float* __restrict__ bias,           // c_attn_b (3072)
    const int* __restrict__ msk,              // (B*SK)
    unsigned short* __restrict__ Qb,          // 4096 x 1024
    unsigned short* __restrict__ Kb,          // 4096 x 1024
    unsigned short* __restrict__ Vtg) {       // (B, NH, HD, SK)
  __shared__ __align__(16) unsigned short Al[2][128 * 64];
  __shared__ __align__(16) unsigned short Bl[2][128 * 64];
  const int tid = threadIdx.x;
  const int l = tid & 63, w = tid >> 6;
  const int wr = w >> 1, wc = w & 1;
  const int lq = l & 15, lh = l >> 4;
  const int bx = blockIdx.x;
  const int m0 = blockIdx.y * 128, n0 = bx * 128;
  const unsigned short* A;
  int lda;
  if (bx < 8) { A = Acat; lda = 2048; } else { A = Aet; lda = 1024; }

  const int swcol = (((tid & 7) ^ ((tid >> 3) & 7)) << 3);
  const int rbase = w * 8 + (l >> 3);
  const unsigned short* gA = A + (long)(m0 + rbase) * lda + swcol;
  const unsigned short* gB = Bw + (long)(n0 + rbase) * 1024 + swcol;

  f32x4 acc[4][4];
#pragma unroll
  for (int a = 0; a < 4; ++a)
#pragma unroll
    for (int b = 0; b < 4; ++b) acc[a][b] = (f32x4){0.f, 0.f, 0.f, 0.f};

  auto stage = [&](int k0, int buf) {
#pragma unroll
    for (int i = 0; i < 4; ++i)
      gl2lds16(gA + (long)(i * 32) * lda + k0, &Al[buf][i * 2048 + w * 512]);
#pragma unroll
    for (int i = 0; i < 4; ++i)
      gl2lds16(gB + (long)(i * 32) * 1024 + k0, &Bl[buf][i * 2048 + w * 512]);
  };

  stage(0, 0);
  __syncthreads();
  int cur = 0;
  for (int t = 0; t < 16; ++t) {
    if (t + 1 < 16) stage((t + 1) << 6, cur ^ 1);
    bf16x8 af[4][2], bfr[4][2];
#pragma unroll
    for (int a = 0; a < 4; ++a) {
      int row = wr * 64 + a * 16 + lq;
#pragma unroll
      for (int kk = 0; kk < 2; ++kk)
        af[a][kk] = *(const bf16x8*)&Al[cur][sidx(row, kk * 64 + lh * 16)];
    }
#pragma unroll
    for (int b = 0; b < 4; ++b) {
      int row = wc * 64 + b * 16 + lq;
#pragma unroll
      for (int kk = 0; kk < 2; ++kk)
        bfr[b][kk] = *(const bf16x8*)&Bl[cur][sidx(row, kk * 64 + lh * 16)];
    }
#pragma unroll
    for (int kk = 0; kk < 2; ++kk)
#pragma unroll
      for (int a = 0; a < 4; ++a)
#pragma unroll
        for (int b = 0; b < 4; ++b)
          acc[a][b] = __builtin_amdgcn_mfma_f32_16x16x32_bf16(
              af[a][kk], bfr[b][kk], acc[a][b], 0, 0, 0);
    __syncthreads();
    cur ^= 1;
  }

#pragma unroll
  for (int a = 0; a < 4; ++a) {
#pragma unroll
    for (int bb = 0; bb < 4; ++bb) {
      int col = n0 + wc * 64 + bb * 16 + lq;
      float bv = bias[col];
      int row0 = m0 + wr * 64 + a * 16 + lh * 4;
      if (col < 1024) {
#pragma unroll
        for (int r = 0; r < 4; ++r)
          Qb[(long)(row0 + r) * 1024 + col] = f2bf(acc[a][bb][r] + bv);
      } else if (col < 2048) {
        int kcol = col - 1024;
#pragma unroll
        for (int r = 0; r < 4; ++r) {
          float mk = (float)msk[row0 + r];
          Kb[(long)(row0 + r) * 1024 + kcol] = f2bf((acc[a][bb][r] + bv) * mk);
        }
      } else {
        int vcol = col - 2048, hh = vcol >> 6, dd = vcol & 63;
        int bi = row0 >> 11, k = row0 & 2047;
        unsigned short t[4];
#pragma unroll
        for (int r = 0; r < 4; ++r) t[r] = f2bf(acc[a][bb][r] + bv);
        *(unsigned long long*)(Vtg + (((long)(bi * NH_ + hh) * HD_ + dd) << 11) + k) =
            *(unsigned long long*)t;
      }
    }
  }
}

// ---------------- flash attention: LDS+swizzle staging, no-max softmax ------
// 1-D grid 1024, XCD-aware decomposition: each XCD owns 4 (b,h) pairs so K/V
// stay L2-resident. Block = 4 waves x 16 q-rows. KV tiles of 64.
// K pre-masked (B*SK, H); V pre-transposed (B, NH, HD, SK).
__global__ __launch_bounds__(256) void flash_attn(
    const unsigned short* __restrict__ Qb,
    const unsigned short* __restrict__ Kb,
    const unsigned short* __restrict__ Vtg,
    unsigned short* __restrict__ Ob, int ldo) {
  __shared__ __align__(16) unsigned short Kl[64 * 64];
  __shared__ __align__(16) unsigned short Vt[64 * 64];  // Vt[d][k]
  __shared__ __align__(16) unsigned short Pl[4][1024];
  const int tid = threadIdx.x;
  const int l = tid & 63, w = tid >> 6;
  const int id = blockIdx.x;
  const int xcd = id & 7, sub = id >> 3;
  const int pair = xcd * 4 + (sub >> 5);  // 0..31 (b*NH+h)
  const int qb = sub & 31;
  const int b = pair >> 4, h = pair & 15;
  const int lq = l & 15, lh = l >> 4;

  const long qrow = (long)b * SQ_ + qb * 64 + w * 16 + lq;
  const unsigned short* qp = Qb + qrow * H_ + h * HD_;
  const bf16x8 qf0 = *(const bf16x8*)(qp + lh * 8);
  const bf16x8 qf1 = *(const bf16x8*)(qp + 32 + lh * 8);

  const int sr = tid >> 2, scs = (tid & 3) * 16;
  const unsigned short* Kg = Kb + ((long)b * SK_ + sr) * H_ + h * HD_ + scs;
  const unsigned short* Vg = Vtg + ((long)(b * NH_ + h) * HD_ + sr) * SK_ + scs;
  const int wi0 = sidx(sr, (tid & 3) * 32);
  const int wi1 = sidx(sr, (tid & 3) * 32 + 16);

  uint4 kr0 = *(const uint4*)Kg, kr1 = *(const uint4*)(Kg + 8);
  uint4 vr0 = *(const uint4*)Vg, vr1 = *(const uint4*)(Vg + 8);
  *(uint4*)&Kl[wi0] = kr0;
  *(uint4*)&Kl[wi1] = kr1;
  *(uint4*)&Vt[wi0] = vr0;
  *(uint4*)&Vt[wi1] = vr1;

  unsigned short* Pw = Pl[w];
  const float C1 = 1.4426950408889634f;   // 1/ln2
  const float C2 = 23.083120654223414f;   // 16/ln2  (P = exp(s-16))
  const bf16x8 vone = {(short)0x3F80, (short)0x3F80, (short)0x3F80, (short)0x3F80,
                       (short)0x3F80, (short)0x3F80, (short)0x3F80, (short)0x3F80};

  f32x4 lacc = (f32x4){0.f, 0.f, 0.f, 0.f};
  f32x4 accO[4];
#pragma unroll
  for (int ms = 0; ms < 4; ++ms) accO[ms] = (f32x4){0.f, 0.f, 0.f, 0.f};

  const int NT = SK_ / 64;
  for (int kt = 0; kt < NT; ++kt) {
    __syncthreads();
    if (kt + 1 < NT) {
      const unsigned short* kp = Kg + (long)(kt + 1) * 64 * H_;
      kr0 = *(const uint4*)kp;
      kr1 = *(const uint4*)(kp + 8);
      vr0 = *(const uint4*)(Vg + (kt + 1) * 64);
      vr1 = *(const uint4*)(Vg + (kt + 1) * 64 + 8);
    }

    f32x4 s[4];
    __builtin_amdgcn_s_setprio(1);
#pragma unroll
    for (int ms = 0; ms < 4; ++ms) {
      int row = ms * 16 + lq;
      bf16x8 a0 = *(const bf16x8*)&Kl[sidx(row, lh * 16)];
      bf16x8 a1 = *(const bf16x8*)&Kl[sidx(row, 64 + lh * 16)];
      f32x4 z = (f32x4){0.f, 0.f, 0.f, 0.f};
      z = __builtin_amdgcn_mfma_f32_16x16x32_bf16(a0, qf0, z, 0, 0, 0);
      z = __builtin_amdgcn_mfma_f32_16x16x32_bf16(a1, qf1, z, 0, 0, 0);
      s[ms] = z;
    }
    __builtin_amdgcn_s_setprio(0);
    // no-max softmax: P = exp(s - 16); row-sum folded into ones-MFMA below
#pragma unroll
    for (int ms = 0; ms < 4; ++ms) {
      float p0 = exp2f(fmaf(s[ms][0], C1, -C2));
      float p1 = exp2f(fmaf(s[ms][1], C1, -C2));
      float p2 = exp2f(fmaf(s[ms][2], C1, -C2));
      float p3 = exp2f(fmaf(s[ms][3], C1, -C2));
      unsigned pk[2] = {cvtpk(p0, p1), cvtpk(p2, p3)};
      *(unsigned long long*)&Pw[sidx(lq, ms * 32 + lh * 8)] =
          *(unsigned long long*)pk;
    }
    bf16x8 pb0 = *(const bf16x8*)&Pw[sidx(lq, lh * 16)];
    bf16x8 pb1 = *(const bf16x8*)&Pw[sidx(lq, 64 + lh * 16)];
    __builtin_amdgcn_s_setprio(1);
#pragma unroll
    for (int ms = 0; ms < 4; ++ms) {
      int row = ms * 16 + lq;
      bf16x8 v0 = *(const bf16x8*)&Vt[sidx(row, lh * 16)];
      bf16x8 v1 = *(const bf16x8*)&Vt[sidx(row, 64 + lh * 16)];
      accO[ms] = __builtin_amdgcn_mfma_f32_16x16x32_bf16(v0, pb0, accO[ms], 0, 0, 0);
      accO[ms] = __builtin_amdgcn_mfma_f32_16x16x32_bf16(v1, pb1, accO[ms], 0, 0, 0);
    }
    lacc = __builtin_amdgcn_mfma_f32_16x16x32_bf16(vone, pb0, lacc, 0, 0, 0);
    lacc = __builtin_amdgcn_mfma_f32_16x16x32_bf16(vone, pb1, lacc, 0, 0, 0);
    __builtin_amdgcn_s_setprio(0);
    __syncthreads();
    if (kt + 1 < NT) {
      *(uint4*)&Kl[wi0] = kr0;
      *(uint4*)&Kl[wi1] = kr1;
      *(uint4*)&Vt[wi0] = vr0;
      *(uint4*)&Vt[wi1] = vr1;
    }
  }

  float rs = 1.f / lacc[0];  // every lane already holds its q's full row-sum
  long orow = (long)b * SQ_ + qb * 64 + w * 16 + lq;
#pragma unroll
  for (int ms = 0; ms < 4; ++ms) {
    unsigned short ou[4];
#pragma unroll
    for (int r = 0; r < 4; ++r) ou[r] = f2bf(accO[ms][r] * rs);
    *(unsigned long long*)(Ob + orow * ldo + h * HD_ + ms * 16 + lh * 4) =
        *(unsigned long long*)ou;
  }
}

extern "C" void kernel_launch(void* const* d_in, const int* in_sizes, int n_in,
                              void* d_out, int out_size, void* d_ws, size_t ws_size,
                              hipStream_t stream) {
  (void)in_sizes; (void)n_in; (void)out_size; (void)ws_size;
  const float* attender = (const float*)d_in[0];
  const float* attendee = (const float*)d_in[1];
  const int*   mask     = (const int*)d_in[2];
  const float* c_attn_w = (const float*)d_in[3];
  const float* c_attn_b = (const float*)d_in[4];
  const float* c_proj_w = (const float*)d_in[5];
  const float* c_proj_b = (const float*)d_in[6];
  const float* mlp_w    = (const float*)d_in[7];
  const float* mlp_b    = (const float*)d_in[8];
  float* out = (float*)d_out;

  char* ws = (char*)d_ws;
  size_t off = 0;
  auto alloc = [&](size_t bytes) {
    void* p = ws + off;
    off += (bytes + 255) & ~(size_t)255;
    return p;
  };
  unsigned short* cat   = (unsigned short*)alloc((size_t)4096 * 2048 * 2); // [attender_bf | attn]
  unsigned short* aet   = (unsigned short*)alloc((size_t)4096 * 1024 * 2);
  unsigned short* w_atT = (unsigned short*)alloc((size_t)3072 * 1024 * 2); // (3H, H)
  unsigned short* w_prT = (unsigned short*)alloc((size_t)1024 * 1024 * 2);
  unsigned short* w_mlT = (unsigned short*)alloc((size_t)1024 * 2048 * 2); // (H, 2H)
  unsigned short* Qb    = (unsigned short*)alloc((size_t)4096 * 1024 * 2);
  unsigned short* Kbuf  = (unsigned short*)alloc((size_t)4096 * 1024 * 2);
  unsigned short* Vtg   = (unsigned short*)alloc((size_t)B_ * NH_ * HD_ * SK_ * 2);
  unsigned short* attnb = (unsigned short*)alloc((size_t)4096 * 1024 * 2);

  conv_bf16<<<2048, 256, 0, stream>>>(attender, cat, 4096, 1024, 1024, 2048);
  conv_bf16<<<2048, 256, 0, stream>>>(attendee, aet, 4096, 1024, 1024, 1024);
  convT<<<768, 256, 0, stream>>>(c_attn_w, w_atT, 1024, 3072);
  convT<<<256, 256, 0, stream>>>(c_proj_w, w_prT, 1024, 1024);
  convT<<<512, 256, 0, stream>>>(mlp_w, w_mlT, 2048, 1024);

  // Q | K*mask | V^T in one launch
  gemm_qkv<<<dim3(24, 32), 256, 0, stream>>>(
      cat, aet, w_atT, c_attn_b, mask, Qb, Kbuf, Vtg);
  // attention -> attnb
  flash_attn<<<1024, 256, 0, stream>>>(Qb, Kbuf, Vtg, attnb, 1024);
  // proj -> cat[:, 1024:2048]
  gemm_bt<2, 0><<<dim3(16, 32), 256, 0, stream>>>(
      attnb, 1024, w_prT, 1024, c_proj_b, cat + 1024, 2048, 1024);
  // out = gelu(cat @ mlp_w + mlp_b), f32
  gemm_bt<2, 1><<<dim3(16, 32), 256, 0, stream>>>(
      cat, 2048, w_mlT, 2048, mlp_b, out, 1024, 2048);
}

// Round 8
// 179.834 us; speedup vs baseline: 1.2061x; 1.0867x over previous
//
#include <hip/hip_runtime.h>
#include <hip/hip_bf16.h>
#include <math.h>

#define H_ 1024
#define NH_ 16
#define HD_ 64
#define B_ 2
#define SQ_ 2048
#define SK_ 2048

using bf16x8 = __attribute__((ext_vector_type(8))) short;
using f32x4  = __attribute__((ext_vector_type(4))) float;
using f32x16 = __attribute__((ext_vector_type(16))) float;

static __device__ __forceinline__ unsigned short f2bf(float f) {
  union { float f; unsigned u; } v; v.f = f;
  unsigned r = v.u + 0x7fffu + ((v.u >> 16) & 1u);
  return (unsigned short)(r >> 16);
}

// two f32 -> packed bf16x2 dword via HW cvt (lo = a, hi = b)
static __device__ __forceinline__ unsigned cvtpk(float a, float b) {
  unsigned r;
  asm("v_cvt_pk_bf16_f32 %0, %1, %2" : "=v"(r) : "v"(a), "v"(b));
  return r;
}

static __device__ __forceinline__ void gl2lds16(const void* g, void* l) {
  __builtin_amdgcn_global_load_lds(
      (const __attribute__((address_space(1))) unsigned int*)g,
      (__attribute__((address_space(3))) unsigned int*)l, 16, 0, 0);
}

// swizzled index (shorts) within a [rows][64-short] tile, 128B rows
static __device__ __forceinline__ int sidx(int row, int cbyte) {
  return row * 64 + (((cbyte) ^ ((row & 7) << 4)) >> 1);
}

// ---------------- f32 -> bf16 convert (8 elems/thread) ----------------
__global__ __launch_bounds__(256) void conv_bf16(
    const float* __restrict__ src, unsigned short* __restrict__ dst,
    int rows, int cols, int ld_src, int ld_dst) {
  long total = (long)rows * cols / 8;
  for (long i = blockIdx.x * (long)blockDim.x + threadIdx.x; i < total;
       i += (long)gridDim.x * blockDim.x) {
    long e = i * 8;
    int r = (int)(e / cols);
    int c = (int)(e % cols);
    const float* s = src + (long)r * ld_src + c;
    unsigned short tmp[8];
#pragma unroll
    for (int j = 0; j < 8; ++j) tmp[j] = f2bf(s[j]);
    *(uint4*)(dst + (long)r * ld_dst + c) = *(uint4*)tmp;
  }
}

// ---------------- f32 (R,C) -> bf16 transposed (C,R) ----------------
__global__ __launch_bounds__(256) void convT(
    const float* __restrict__ in, unsigned short* __restrict__ out, int R, int C) {
  __shared__ __align__(16) unsigned short Ls[64][68];
  int nct = C >> 6;
  int tr = blockIdx.x / nct, tc = blockIdx.x % nct;
  int r0 = tr * 64, c0 = tc * 64;
  int rr = threadIdx.x >> 4;
  int cc = (threadIdx.x & 15) * 4;
#pragma unroll
  for (int i = 0; i < 4; ++i) {
    int r = rr + 16 * i;
    float4 v = *(const float4*)&in[(long)(r0 + r) * C + c0 + cc];
    unsigned short t[4] = {f2bf(v.x), f2bf(v.y), f2bf(v.z), f2bf(v.w)};
    *(unsigned long long*)&Ls[r][cc] = *(unsigned long long*)t;
  }
  __syncthreads();
  int oc = threadIdx.x >> 2;
  int orr = (threadIdx.x & 3) * 16;
  unsigned short t[16];
#pragma unroll
  for (int j = 0; j < 16; ++j) t[j] = Ls[orr + j][oc];
  *(uint4*)&out[(long)(c0 + oc) * R + r0 + orr] = *(uint4*)&t[0];
  *(uint4*)&out[(long)(c0 + oc) * R + r0 + orr + 8] = *(uint4*)&t[8];
}

// ---------------- bf16 GEMM, B^T input, BK=64, double-buffered, swizzled ----
// Out = A(MxK) @ W(KxN) + bias, Bw = W^T (N rows, K cols). BN = NF*32.
// MODE 0: bf16 out0 (scaled by oscale). MODE 1: f32 out0 + GELU.
// MODE 2: split KV (col<H -> bf16 K*mask to out0; col>=H -> V^T to out1).
template <int NF, int MODE>
__global__ __launch_bounds__(256) void gemm_bt(
    const unsigned short* __restrict__ A, int lda,
    const unsigned short* __restrict__ Bw, int ldb,
    const float* __restrict__ bias, const int* __restrict__ msk, float oscale,
    void* __restrict__ out0, void* __restrict__ out1, int ldo, int K) {
  __shared__ __align__(16) unsigned short Al[2][128 * 64];
  __shared__ __align__(16) unsigned short Bl[2][NF * 32 * 64];
  const int tid = threadIdx.x;
  const int l = tid & 63, w = tid >> 6;
  const int wr = w >> 1, wc = w & 1;
  const int lq = l & 15, lh = l >> 4;
  const int m0 = blockIdx.y * 128, n0 = blockIdx.x * (NF * 32);

  const int swcol = (((tid & 7) ^ ((tid >> 3) & 7)) << 3);  // shorts
  const int rbase = w * 8 + (l >> 3);
  const unsigned short* gA = A + (long)(m0 + rbase) * lda + swcol;
  const unsigned short* gB = Bw + (long)(n0 + rbase) * ldb + swcol;

  f32x4 acc[4][NF];
#pragma unroll
  for (int a = 0; a < 4; ++a)
#pragma unroll
    for (int b = 0; b < NF; ++b) acc[a][b] = (f32x4){0.f, 0.f, 0.f, 0.f};

  auto stage = [&](int k0, int buf) {
#pragma unroll
    for (int i = 0; i < 4; ++i)
      gl2lds16(gA + (long)(i * 32) * lda + k0, &Al[buf][i * 2048 + w * 512]);
#pragma unroll
    for (int i = 0; i < NF; ++i)
      gl2lds16(gB + (long)(i * 32) * ldb + k0, &Bl[buf][i * 2048 + w * 512]);
  };

  const int NT = K >> 6;
  stage(0, 0);
  __syncthreads();
  int cur = 0;
  for (int t = 0; t < NT; ++t) {
    if (t + 1 < NT) stage((t + 1) << 6, cur ^ 1);
    bf16x8 af[4][2], bfr[NF][2];
#pragma unroll
    for (int a = 0; a < 4; ++a) {
      int row = wr * 64 + a * 16 + lq;
#pragma unroll
      for (int kk = 0; kk < 2; ++kk)
        af[a][kk] = *(const bf16x8*)&Al[cur][sidx(row, kk * 64 + lh * 16)];
    }
#pragma unroll
    for (int b = 0; b < NF; ++b) {
      int row = wc * (NF * 16) + b * 16 + lq;
#pragma unroll
      for (int kk = 0; kk < 2; ++kk)
        bfr[b][kk] = *(const bf16x8*)&Bl[cur][sidx(row, kk * 64 + lh * 16)];
    }
#pragma unroll
    for (int kk = 0; kk < 2; ++kk)
#pragma unroll
      for (int a = 0; a < 4; ++a)
#pragma unroll
        for (int b = 0; b < NF; ++b)
          acc[a][b] = __builtin_amdgcn_mfma_f32_16x16x32_bf16(
              af[a][kk], bfr[b][kk], acc[a][b], 0, 0, 0);
    __syncthreads();
    cur ^= 1;
  }

#pragma unroll
  for (int a = 0; a < 4; ++a) {
#pragma unroll
    for (int bb = 0; bb < NF; ++bb) {
      int col = n0 + wc * (NF * 16) + bb * 16 + lq;
      float bv = bias[col];
      int row0 = m0 + wr * 64 + a * 16 + lh * 4;
      if (MODE == 0) {
        unsigned short* O = (unsigned short*)out0;
#pragma unroll
        for (int r = 0; r < 4; ++r)
          O[(long)(row0 + r) * ldo + col] = f2bf((acc[a][bb][r] + bv) * oscale);
      } else if (MODE == 1) {
        float* O = (float*)out0;
#pragma unroll
        for (int r = 0; r < 4; ++r) {
          float v = acc[a][bb][r] + bv;
          float y = 0.7978845608028654f * (v + 0.044715f * v * v * v);
          O[(long)(row0 + r) * ldo + col] =
              v * __builtin_amdgcn_rcpf(1.f + __expf(-2.f * y));
        }
      } else {
        if (col < H_) {
          unsigned short* O = (unsigned short*)out0;
#pragma unroll
          for (int r = 0; r < 4; ++r) {
            float mk = (float)msk[row0 + r];
            O[(long)(row0 + r) * ldo + col] = f2bf((acc[a][bb][r] + bv) * mk);
          }
        } else {
          int vcol = col - H_, hh = vcol >> 6, dd = vcol & 63;
          int bi = row0 >> 11, k = row0 & 2047;
          unsigned short t[4];
#pragma unroll
          for (int r = 0; r < 4; ++r) t[r] = f2bf(acc[a][bb][r] + bv);
          *(unsigned long long*)((unsigned short*)out1 +
                                 (((long)(bi * NH_ + hh) * HD_ + dd) << 11) + k) =
              *(unsigned long long*)t;
        }
      }
    }
  }
}

// ---------------- flash attention: 32x32 MFMA, in-register P (T12) ----------
// grid 512 (XCD-remapped), block = 4 waves x 32 q. KV tiles of 64.
// Q pre-scaled by log2(e); K pre-masked; V pre-transposed (B,NH,HD,SK).
// Swapped QK^T: S^T = K·Q^T so lane owns q = lane&31; P assembled in regs via
// cvt_pk + permlane32_swap; P never touches LDS.
__global__ __launch_bounds__(256) void flash_attn(
    const unsigned short* __restrict__ Qb,
    const unsigned short* __restrict__ Kb,
    const unsigned short* __restrict__ Vtg,
    unsigned short* __restrict__ Ob) {
  __shared__ __align__(16) unsigned short Kl[2][64 * 64];
  __shared__ __align__(16) unsigned short Vl[2][64 * 64];
  __shared__ __align__(16) float Lr[4][32];
  const int tid = threadIdx.x;
  const int l = tid & 63, w = tid >> 6;
  const int lo = l & 31, hi = l >> 5;
  const int id = blockIdx.x;
  const int xcd = id & 7, sub = id >> 3;
  const int pair = xcd * 4 + (sub >> 4);  // (b*NH+h): 4 pairs per XCD
  const int qb = sub & 15;
  const int b = pair >> 4, h = pair & 15;
  const int brow = b * SQ_ + qb * 128 + w * 32;

  // Q B-fragments (32x32x16: lane holds Q[q=lo][d = dstep*16 + hi*8 + j])
  bf16x8 qf[4];
  {
    const unsigned short* qp = Qb + (long)(brow + lo) * H_ + h * HD_ + hi * 8;
#pragma unroll
    for (int d = 0; d < 4; ++d) qf[d] = *(const bf16x8*)(qp + d * 16);
  }

  // staging: lane covers rows j*32 + w*8 + (l>>3), bytecol (l&7)*16 (j=0,1);
  // source col pre-swizzled so linear LDS dest lands XOR-swizzled (rule #21)
  const int srow = w * 8 + (l >> 3);
  const int swc = ((l & 7) ^ ((l >> 3) & 7)) << 3;  // shorts
  const unsigned short* Kg = Kb + ((long)b * SK_ + srow) * H_ + h * HD_ + swc;
  const unsigned short* Vg = Vtg + ((long)(b * NH_ + h) * HD_ + srow) * SK_ + swc;

  auto stage = [&](int kt, int buf) {
    const unsigned short* ks = Kg + (long)kt * 64 * H_;
    const unsigned short* vs = Vg + kt * 64;
    char* kd = (char*)&Kl[buf][0] + w * 1024;
    char* vd = (char*)&Vl[buf][0] + w * 1024;
    gl2lds16(ks, kd);
    gl2lds16(ks + (long)32 * H_, kd + 4096);
    gl2lds16(vs, vd);
    gl2lds16(vs + (long)32 * SK_, vd + 4096);
  };

  f32x16 accO[2];
#pragma unroll
  for (int i = 0; i < 2; ++i)
#pragma unroll
    for (int r = 0; r < 16; ++r) accO[i][r] = 0.f;
  float l_run = 0.f;

  stage(0, 0);
  __syncthreads();
  int cur = 0;
  const int NT = SK_ / 64;
  for (int kt = 0; kt < NT; ++kt) {
    if (kt + 1 < NT) stage(kt + 1, cur ^ 1);
    const unsigned short* Kc = &Kl[cur][0];
    const unsigned short* Vc = &Vl[cur][0];

    // S^T[k][q] = K_tile(64x64) @ Q^T(64x32): two 32x32 halves over k
    f32x16 s0, s1;
#pragma unroll
    for (int r = 0; r < 16; ++r) { s0[r] = 0.f; s1[r] = 0.f; }
    __builtin_amdgcn_s_setprio(1);
#pragma unroll
    for (int ds = 0; ds < 4; ++ds) {
      bf16x8 ka0 = *(const bf16x8*)&Kc[sidx(lo, ds * 32 + hi * 16)];
      bf16x8 ka1 = *(const bf16x8*)&Kc[sidx(32 + lo, ds * 32 + hi * 16)];
      s0 = __builtin_amdgcn_mfma_f32_32x32x16_bf16(ka0, qf[ds], s0, 0, 0, 0);
      s1 = __builtin_amdgcn_mfma_f32_32x32x16_bf16(ka1, qf[ds], s1, 0, 0, 0);
    }
    __builtin_amdgcn_s_setprio(0);

    // P = 2^s (Q carries log2e; shift-free, cancels in normalization).
    // Lane holds, for q=lo, k = kh*32 + 4*hi + {(r&3)+8*(r>>2)}.
    // Assemble PV A-frags (k = kstep*16 + hi*8 + j) via cvt_pk + permlane32.
    bf16x8 pa[4];
    float ps = 0.f;
#pragma unroll
    for (int kh = 0; kh < 2; ++kh) {
      const f32x16& s = kh ? s1 : s0;
      float p[16];
#pragma unroll
      for (int r = 0; r < 16; ++r) { p[r] = exp2f(s[r]); ps += p[r]; }
#pragma unroll
      for (int g = 0; g < 2; ++g) {
        unsigned X0 = cvtpk(p[g * 8 + 0], p[g * 8 + 1]);
        unsigned X1 = cvtpk(p[g * 8 + 2], p[g * 8 + 3]);
        unsigned Y0 = cvtpk(p[g * 8 + 4], p[g * 8 + 5]);
        unsigned Y1 = cvtpk(p[g * 8 + 6], p[g * 8 + 7]);
        asm("v_permlane32_swap_b32 %0, %1" : "+v"(X0), "+v"(Y0));
        asm("v_permlane32_swap_b32 %0, %1" : "+v"(X1), "+v"(Y1));
        union { unsigned u[4]; bf16x8 v; } cc;
        cc.u[0] = X0; cc.u[1] = X1; cc.u[2] = Y0; cc.u[3] = Y1;
        pa[kh * 2 + g] = cc.v;
      }
    }
    l_run += ps;

    // O[q][d] += P(32x64) @ V(64x64): two 32x32 outputs over d
    __builtin_amdgcn_s_setprio(1);
#pragma unroll
    for (int dh = 0; dh < 2; ++dh)
#pragma unroll
      for (int ks = 0; ks < 4; ++ks) {
        bf16x8 vb = *(const bf16x8*)&Vc[sidx(dh * 32 + lo, ks * 32 + hi * 16)];
        accO[dh] = __builtin_amdgcn_mfma_f32_32x32x16_bf16(pa[ks], vb, accO[dh], 0, 0, 0);
      }
    __builtin_amdgcn_s_setprio(0);
    __syncthreads();
    cur ^= 1;
  }

  // row-sum: own half + partner half (lanes l, l^32 share q = l&31)
  l_run += __shfl_xor(l_run, 32);
  if (l < 32) Lr[w][lo] = __builtin_amdgcn_rcpf(l_run);
  // redistribute 1/l to the C-layout (q = 4*hi + (r&3) + 8*(r>>2))
  f32x4 rsq[4];
#pragma unroll
  for (int rq = 0; rq < 4; ++rq)
    rsq[rq] = *(const f32x4*)&Lr[w][4 * hi + 8 * rq];

#pragma unroll
  for (int dh = 0; dh < 2; ++dh) {
#pragma unroll
    for (int r = 0; r < 16; ++r) {
      int qm = 4 * hi + (r & 3) + 8 * (r >> 2);
      float v = accO[dh][r] * rsq[r >> 2][r & 3];
      Ob[(long)(brow + qm) * H_ + h * HD_ + dh * 32 + lo] = f2bf(v);
    }
  }
}

extern "C" void kernel_launch(void* const* d_in, const int* in_sizes, int n_in,
                              void* d_out, int out_size, void* d_ws, size_t ws_size,
                              hipStream_t stream) {
  (void)in_sizes; (void)n_in; (void)out_size; (void)ws_size;
  const float* attender = (const float*)d_in[0];
  const float* attendee = (const float*)d_in[1];
  const int*   mask     = (const int*)d_in[2];
  const float* c_attn_w = (const float*)d_in[3];
  const float* c_attn_b = (const float*)d_in[4];
  const float* c_proj_w = (const float*)d_in[5];
  const float* c_proj_b = (const float*)d_in[6];
  const float* mlp_w    = (const float*)d_in[7];
  const float* mlp_b    = (const float*)d_in[8];
  float* out = (float*)d_out;

  char* ws = (char*)d_ws;
  size_t off = 0;
  auto alloc = [&](size_t bytes) {
    void* p = ws + off;
    off += (bytes + 255) & ~(size_t)255;
    return p;
  };
  unsigned short* cat   = (unsigned short*)alloc((size_t)4096 * 2048 * 2); // [attender_bf | attn]
  unsigned short* aet   = (unsigned short*)alloc((size_t)4096 * 1024 * 2);
  unsigned short* w_atT = (unsigned short*)alloc((size_t)3072 * 1024 * 2); // (3H, H)
  unsigned short* w_prT = (unsigned short*)alloc((size_t)1024 * 1024 * 2);
  unsigned short* w_mlT = (unsigned short*)alloc((size_t)1024 * 2048 * 2); // (H, 2H)
  unsigned short* Qb    = (unsigned short*)alloc((size_t)4096 * 1024 * 2);
  unsigned short* Kbuf  = (unsigned short*)alloc((size_t)4096 * 1024 * 2);
  unsigned short* Vtg   = (unsigned short*)alloc((size_t)B_ * NH_ * HD_ * SK_ * 2);
  unsigned short* attnb = (unsigned short*)alloc((size_t)4096 * 1024 * 2);

  const float LOG2E = 1.4426950408889634f;

  conv_bf16<<<2048, 256, 0, stream>>>(attender, cat, 4096, 1024, 1024, 2048);
  conv_bf16<<<2048, 256, 0, stream>>>(attendee, aet, 4096, 1024, 1024, 1024);
  convT<<<768, 256, 0, stream>>>(c_attn_w, w_atT, 1024, 3072);
  convT<<<256, 256, 0, stream>>>(c_proj_w, w_prT, 1024, 1024);
  convT<<<512, 256, 0, stream>>>(mlp_w, w_mlT, 2048, 1024);

  // Q = (attender @ W[:, :H] + b) * log2(e)
  gemm_bt<2, 0><<<dim3(16, 32), 256, 0, stream>>>(
      cat, 2048, w_atT, 1024, c_attn_b, nullptr, LOG2E, Qb, nullptr, 1024, 1024);
  // K,V: K masked+normal, V transposed
  gemm_bt<4, 2><<<dim3(16, 32), 256, 0, stream>>>(
      aet, 1024, w_atT + (size_t)1024 * 1024, 1024, c_attn_b + 1024, mask, 1.f,
      Kbuf, Vtg, 1024, 1024);
  // attention -> attnb
  flash_attn<<<512, 256, 0, stream>>>(Qb, Kbuf, Vtg, attnb);
  // proj -> cat[:, 1024:2048]
  gemm_bt<2, 0><<<dim3(16, 32), 256, 0, stream>>>(
      attnb, 1024, w_prT, 1024, c_proj_b, nullptr, 1.f, cat + 1024, nullptr, 2048, 1024);
  // out = gelu(cat @ mlp_w + mlp_b), f32
  gemm_bt<2, 1><<<dim3(16, 32), 256, 0, stream>>>(
      cat, 2048, w_mlT, 2048, mlp_b, nullptr, 1.f, out, nullptr, 1024, 2048);
}